// Round 11
// baseline (371.397 us; speedup 1.0000x reference)
//
#include <hip/hip_runtime.h>

// ForgetMult: h_t = f_t*x_t + (1-f_t)*h_{t-1}, shapes (S=4096, B=16, H=512) fp32.
// R14 = R13 with stream-separated load issue in fm_agg.
// Evidence: fm_apply runs ~5.9 TB/s app (LLC-warm reads + NT writes), fm_agg
// pinned at ~2.7 TB/s across occupancy/MLP/contiguity/clustering probes. The
// one pattern unique to fm_agg: strict f,x,f,x load alternation at instruction
// granularity with f/x exactly 2^27 B apart (same-bank-aligned) => DRAM
// row-buffer ping-pong on the miss path. Fix: per 8-row batch, issue a RUN of
// 8 f-loads, then a RUN of 8 x-loads (sched_barrier(0) fences keep the runs
// intact), then compute 8 steps in unchanged t-order (bit-identical math).

#define SQ      4096
#define NC4     2048            // float4 columns = 16*512/4
#define NCH     8192            // scalar chains
#define TT      64              // timesteps per chunk
#define NCHUNK  (SQ / TT)       // 64
#define GRID1   (NCHUNK * 8)    // 512 blocks for K1/K3

typedef float floatx4 __attribute__((ext_vector_type(4)));

#define FM_B(B,F,X) \
  B.x = fmaf(F.x, X.x - B.x, B.x); B.y = fmaf(F.y, X.y - B.y, B.y); \
  B.z = fmaf(F.z, X.z - B.z, B.z); B.w = fmaf(F.w, X.w - B.w, B.w);
#define FM_A(A,F) \
  A.x = fmaf(-F.x, A.x, A.x); A.y = fmaf(-F.y, A.y, A.y); \
  A.z = fmaf(-F.z, A.z, A.z); A.w = fmaf(-F.w, A.w, A.w);

// ---- K1: per-chunk aggregates A = prod(1-f), B = local scan ----
// Stream-separated issue: 8 f-loads, fence, 8 x-loads, fence, 8 compute steps.
__global__ __launch_bounds__(256, 2)
void fm_agg(const floatx4* __restrict__ f4, const floatx4* __restrict__ x4,
            floatx4* __restrict__ aggA, floatx4* __restrict__ aggB)
{
  const int tid   = threadIdx.x;
  const int chunk = blockIdx.x >> 3;
  const int col   = ((blockIdx.x & 7) << 8) + tid;
  const size_t base = (size_t)(chunk * TT) * NC4 + col;

  floatx4 A = {1.f,1.f,1.f,1.f}, B = {0.f,0.f,0.f,0.f};

  for (int bb = 0; bb < TT / 8; ++bb) {
    floatx4 ff[8], xx[8];
#pragma unroll
    for (int i = 0; i < 8; ++i)
      ff[i] = f4[base + (size_t)(bb * 8 + i) * NC4];
    __builtin_amdgcn_sched_barrier(0);   // keep the f-run contiguous
#pragma unroll
    for (int i = 0; i < 8; ++i)
      xx[i] = x4[base + (size_t)(bb * 8 + i) * NC4];
    __builtin_amdgcn_sched_barrier(0);   // keep the x-run contiguous
#pragma unroll
    for (int i = 0; i < 8; ++i) {
      FM_B(B, ff[i], xx[i])  FM_A(A, ff[i])
    }
  }
  aggA[(size_t)chunk * NC4 + col] = A;
  aggB[(size_t)chunk * NC4 + col] = B;
}

// ---- K2: scan chunk aggregates per scalar chain, hprev written IN PLACE ----
__global__ __launch_bounds__(256, 4)
void fm_mid(const float* __restrict__ A, float* __restrict__ B,
            const float* __restrict__ h0)
{
  const int chain = blockIdx.x * 256 + threadIdx.x;
  float h = h0[chain];
  for (int cb = 0; cb < NCHUNK / 16; ++cb) {
    float a[16], b[16];
#pragma unroll
    for (int i = 0; i < 16; ++i) {
      const size_t idx = (size_t)(cb * 16 + i) * NCH + chain;
      a[i] = A[idx];
      b[i] = B[idx];
    }
#pragma unroll
    for (int i = 0; i < 16; ++i) {
      const size_t idx = (size_t)(cb * 16 + i) * NCH + chain;
      B[idx] = h;                    // hprev entering chunk cb*16+i
      h = fmaf(a[i], h, b[i]);
    }
  }
}

// ---- K3: apply recurrence from hprev (= aggB), descending chunks, NT out ----
__global__ __launch_bounds__(256, 4)
void fm_apply(const floatx4* __restrict__ f4, const floatx4* __restrict__ x4,
              const floatx4* __restrict__ hprev4, floatx4* __restrict__ out4)
{
  const int tid   = threadIdx.x;
  const int chunk = (NCHUNK - 1) - (blockIdx.x >> 3);   // descending: LLC reuse
  const int col   = ((blockIdx.x & 7) << 8) + tid;
  const size_t base = (size_t)(chunk * TT) * NC4 + col;

  floatx4 h = hprev4[(size_t)chunk * NC4 + col];
#pragma unroll 8
  for (int t = 0; t < TT; ++t) {
    const floatx4 F = f4[base + (size_t)t * NC4];
    const floatx4 X = x4[base + (size_t)t * NC4];
    FM_B(h, F, X)
    // Nontemporal: don't let the 128 MB output stream evict f,x from LLC.
    __builtin_nontemporal_store(h, &out4[base + (size_t)t * NC4]);
  }
}

// Fallback (only if ws_size is too small): one float4-column per thread.
__global__ void fm_naive(const floatx4* __restrict__ f4, const floatx4* __restrict__ x4,
                         const floatx4* __restrict__ h04, floatx4* __restrict__ out4)
{
  const int col = blockIdx.x * blockDim.x + threadIdx.x;
  if (col >= NC4) return;
  floatx4 h = h04[col];
  for (int t = 0; t < SQ; ++t) {
    const size_t idx = (size_t)t * NC4 + col;
    const floatx4 F = f4[idx], X = x4[idx];
    FM_B(h, F, X)
    out4[idx] = h;
  }
}

extern "C" void kernel_launch(void* const* d_in, const int* in_sizes, int n_in,
                              void* d_out, int out_size, void* d_ws, size_t ws_size,
                              hipStream_t stream)
{
  const floatx4* f4  = (const floatx4*)d_in[0];
  const floatx4* x4  = (const floatx4*)d_in[1];
  const float*   h0  = (const float*)d_in[2];
  floatx4* out4 = (floatx4*)d_out;

  const size_t AGG = (size_t)NCHUNK * NC4 * 16;   // 2 MB per aggregate array

  if (ws_size >= 2 * AGG) {                        // 4 MB needed
    floatx4* aggA = (floatx4*)d_ws;
    floatx4* aggB = (floatx4*)((char*)d_ws + AGG);
    fm_agg<<<GRID1, 256, 0, stream>>>(f4, x4, aggA, aggB);
    fm_mid<<<NCH / 256, 256, 0, stream>>>((const float*)aggA,
                                          (float*)aggB, h0);
    fm_apply<<<GRID1, 256, 0, stream>>>(f4, x4, (const floatx4*)aggB, out4);
  } else {
    fm_naive<<<(NC4 + 255) / 256, 256, 0, stream>>>(f4, x4,
                                                    (const floatx4*)h0, out4);
  }
}

// Round 12
// 369.996 us; speedup vs baseline: 1.0038x; 1.0038x over previous
//
#include <hip/hip_runtime.h>

// ForgetMult: h_t = f_t*x_t + (1-f_t)*h_{t-1}, shapes (S=4096, B=16, H=512) fp32.
// R15: REALLY force MLP in fm_agg via volatile inline-asm loads.
// Evidence this was never tested: R10's "32-load batch" compiled to VGPR=68,
// R14's "8+8 batch" to VGPR=44 -- both physically impossible if the loads were
// actually batched (need 128/64 live data regs). The backend re-serialized
// every C-level batching attempt; sched_barrier(0) alone did not hold.
// Volatile asm global_load_dwordx4 preserves program order through ALL passes
// and forces all 32 results live -> true MLP=32 per thread. Consume after
// s_waitcnt vmcnt(0) + sched_barrier(0) (guide rule #18), t-order unchanged
// (bit-identical math). K2/K3 = proven R13 versions (total 361us).

#define SQ      4096
#define NC4     2048            // float4 columns = 16*512/4
#define NCH     8192            // scalar chains
#define TT      64              // timesteps per chunk
#define NCHUNK  (SQ / TT)       // 64
#define GRID1   (NCHUNK * 8)    // 512 blocks for K1/K3

typedef float floatx4 __attribute__((ext_vector_type(4)));

#define FM_B(B,F,X) \
  B.x = fmaf(F.x, X.x - B.x, B.x); B.y = fmaf(F.y, X.y - B.y, B.y); \
  B.z = fmaf(F.z, X.z - B.z, B.z); B.w = fmaf(F.w, X.w - B.w, B.w);
#define FM_A(A,F) \
  A.x = fmaf(-F.x, A.x, A.x); A.y = fmaf(-F.y, A.y, A.y); \
  A.z = fmaf(-F.z, A.z, A.z); A.w = fmaf(-F.w, A.w, A.w);

// ---- K1: per-chunk aggregates A = prod(1-f), B = local scan ----
// Per 16-row batch: 16 f-loads + 16 x-loads as volatile asm (forced in
// flight), single vmcnt(0) drain, then 16 compute steps in t-order.
__global__ __launch_bounds__(256, 2)
void fm_agg(const floatx4* __restrict__ f4, const floatx4* __restrict__ x4,
            floatx4* __restrict__ aggA, floatx4* __restrict__ aggB)
{
  const int tid   = threadIdx.x;
  const int chunk = blockIdx.x >> 3;
  const int col   = ((blockIdx.x & 7) << 8) + tid;
  const size_t base = (size_t)(chunk * TT) * NC4 + col;

  floatx4 A = {1.f,1.f,1.f,1.f}, B = {0.f,0.f,0.f,0.f};

  for (int bb = 0; bb < TT / 16; ++bb) {
    floatx4 ff[16], xx[16];
#pragma unroll
    for (int i = 0; i < 16; ++i) {
      const floatx4* p = f4 + base + (size_t)(bb * 16 + i) * NC4;
      asm volatile("global_load_dwordx4 %0, %1, off"
                   : "=v"(ff[i]) : "v"(p) : "memory");
    }
#pragma unroll
    for (int i = 0; i < 16; ++i) {
      const floatx4* p = x4 + base + (size_t)(bb * 16 + i) * NC4;
      asm volatile("global_load_dwordx4 %0, %1, off"
                   : "=v"(xx[i]) : "v"(p) : "memory");
    }
    asm volatile("s_waitcnt vmcnt(0)" ::: "memory");
    __builtin_amdgcn_sched_barrier(0);   // rule #18: no hoisting past waitcnt
#pragma unroll
    for (int i = 0; i < 16; ++i) {
      FM_B(B, ff[i], xx[i])  FM_A(A, ff[i])
    }
  }
  aggA[(size_t)chunk * NC4 + col] = A;
  aggB[(size_t)chunk * NC4 + col] = B;
}

// ---- K2: scan chunk aggregates per scalar chain, hprev written IN PLACE ----
__global__ __launch_bounds__(256, 4)
void fm_mid(const float* __restrict__ A, float* __restrict__ B,
            const float* __restrict__ h0)
{
  const int chain = blockIdx.x * 256 + threadIdx.x;
  float h = h0[chain];
  for (int cb = 0; cb < NCHUNK / 16; ++cb) {
    float a[16], b[16];
#pragma unroll
    for (int i = 0; i < 16; ++i) {
      const size_t idx = (size_t)(cb * 16 + i) * NCH + chain;
      a[i] = A[idx];
      b[i] = B[idx];
    }
#pragma unroll
    for (int i = 0; i < 16; ++i) {
      const size_t idx = (size_t)(cb * 16 + i) * NCH + chain;
      B[idx] = h;                    // hprev entering chunk cb*16+i
      h = fmaf(a[i], h, b[i]);
    }
  }
}

// ---- K3: apply recurrence from hprev (= aggB), descending chunks, NT out ----
__global__ __launch_bounds__(256, 4)
void fm_apply(const floatx4* __restrict__ f4, const floatx4* __restrict__ x4,
              const floatx4* __restrict__ hprev4, floatx4* __restrict__ out4)
{
  const int tid   = threadIdx.x;
  const int chunk = (NCHUNK - 1) - (blockIdx.x >> 3);   // descending: LLC reuse
  const int col   = ((blockIdx.x & 7) << 8) + tid;
  const size_t base = (size_t)(chunk * TT) * NC4 + col;

  floatx4 h = hprev4[(size_t)chunk * NC4 + col];
#pragma unroll 8
  for (int t = 0; t < TT; ++t) {
    const floatx4 F = f4[base + (size_t)t * NC4];
    const floatx4 X = x4[base + (size_t)t * NC4];
    FM_B(h, F, X)
    // Nontemporal: don't let the 128 MB output stream evict f,x from LLC.
    __builtin_nontemporal_store(h, &out4[base + (size_t)t * NC4]);
  }
}

// Fallback (only if ws_size is too small): one float4-column per thread.
__global__ void fm_naive(const floatx4* __restrict__ f4, const floatx4* __restrict__ x4,
                         const floatx4* __restrict__ h04, floatx4* __restrict__ out4)
{
  const int col = blockIdx.x * blockDim.x + threadIdx.x;
  if (col >= NC4) return;
  floatx4 h = h04[col];
  for (int t = 0; t < SQ; ++t) {
    const size_t idx = (size_t)t * NC4 + col;
    const floatx4 F = f4[idx], X = x4[idx];
    FM_B(h, F, X)
    out4[idx] = h;
  }
}

extern "C" void kernel_launch(void* const* d_in, const int* in_sizes, int n_in,
                              void* d_out, int out_size, void* d_ws, size_t ws_size,
                              hipStream_t stream)
{
  const floatx4* f4  = (const floatx4*)d_in[0];
  const floatx4* x4  = (const floatx4*)d_in[1];
  const float*   h0  = (const float*)d_in[2];
  floatx4* out4 = (floatx4*)d_out;

  const size_t AGG = (size_t)NCHUNK * NC4 * 16;   // 2 MB per aggregate array

  if (ws_size >= 2 * AGG) {                        // 4 MB needed
    floatx4* aggA = (floatx4*)d_ws;
    floatx4* aggB = (floatx4*)((char*)d_ws + AGG);
    fm_agg<<<GRID1, 256, 0, stream>>>(f4, x4, aggA, aggB);
    fm_mid<<<NCH / 256, 256, 0, stream>>>((const float*)aggA,
                                          (float*)aggB, h0);
    fm_apply<<<GRID1, 256, 0, stream>>>(f4, x4, (const floatx4*)aggB, out4);
  } else {
    fm_naive<<<(NC4 + 255) / 256, 256, 0, stream>>>(f4, x4,
                                                    (const floatx4*)h0, out4);
  }
}